// Round 12
// baseline (343.780 us; speedup 1.0000x reference)
//
#include <hip/hip_runtime.h>

#define LRELU 0.01f

// ---------------- problem constants ----------------
// relations: 0 follows U->U, 1 posts U->N, 2 posted_by N->U, 3 publishes S->N, 4 published_by N->S
static const int kNU = 50000, kNN = 20000, kNS = 2000;
static const int DOUT_OFF[5] = {0, 100000, 170000, 240000, 262000};
static const int DIN_OFF[5]  = {50000, 150000, 190000, 242000, 282000};
static const int RP_OFF[5]   = {0, 50001, 70002, 120003, 140004};
static const int CSR_OFF[5]  = {0, 500000, 800000, 1100000, 1250000};

using bf16x8 = __attribute__((ext_vector_type(8))) short;
using u16x8  = __attribute__((ext_vector_type(8))) unsigned short;
using f32x4  = __attribute__((ext_vector_type(4))) float;

__device__ __forceinline__ float bf2f(unsigned short u) {
  return __uint_as_float(((unsigned)u) << 16);
}
__device__ __forceinline__ unsigned short f2bf(float f) {  // RNE
  unsigned u = __float_as_uint(f);
  u += 0x7FFFu + ((u >> 16) & 1u);
  return (unsigned short)(u >> 16);
}

// ---------------- phase A: packed-u16 LDS histograms + transform(L1) + wprep ----------------
// 16384 nodes per 32KB range via 2-packed u16 bins; rank = (old>>shift)&0xffff.
// Per-(node,chunk) counts << 65536 so the packed atomicAdd never carries across.

struct TJob { const float* X; const float* W; unsigned short* Y; int M; };
struct PrepJob { const float* W0; unsigned short* hi; unsigned short* lo;
                 int NOUT; int bstart; };
struct AArgs { const int* esrc[5]; const int* edst[5]; int* pos; int* partial;
               TJob tj[5]; PrepJob pj[8]; };

__device__ __forceinline__ void transform_body(const TJob& p, int bxl, int t) {
  int w = t >> 6, l = t & 63;
  int lo16 = l & 15, hi4 = l >> 4;
  int m0 = bxl * 64;
  int M = p.M;
  f32x4 acc[4][2] = {};
  for (int s = 0; s < 4; ++s) {  // K = 128, 32 per step
    int kbase = s * 32 + hi4 * 8;
    bf16x8 af[4];
#pragma unroll
    for (int mf = 0; mf < 4; ++mf) {
      int row = m0 + mf * 16 + lo16;
      row = row < M ? row : M - 1;  // clamp; OOB rows never stored
      const float* xr = &p.X[(size_t)row * 128 + kbase];
      float4 xa = *(const float4*)xr;
      float4 xb = *(const float4*)(xr + 4);
      af[mf][0] = (short)f2bf(xa.x); af[mf][1] = (short)f2bf(xa.y);
      af[mf][2] = (short)f2bf(xa.z); af[mf][3] = (short)f2bf(xa.w);
      af[mf][4] = (short)f2bf(xb.x); af[mf][5] = (short)f2bf(xb.y);
      af[mf][6] = (short)f2bf(xb.z); af[mf][7] = (short)f2bf(xb.w);
    }
#pragma unroll
    for (int nf = 0; nf < 2; ++nf) {
      int n = (w * 2 + nf) * 16 + lo16;
      bf16x8 bh, bl;
#pragma unroll
      for (int j = 0; j < 8; ++j) {
        float wv = p.W[(size_t)(kbase + j) * 128 + n];
        unsigned short h = f2bf(wv);
        bh[j] = (short)h;
        bl[j] = (short)f2bf(wv - bf2f(h));
      }
#pragma unroll
      for (int mf = 0; mf < 4; ++mf) {
        acc[mf][nf] = __builtin_amdgcn_mfma_f32_16x16x32_bf16(af[mf], bh, acc[mf][nf], 0, 0, 0);
        acc[mf][nf] = __builtin_amdgcn_mfma_f32_16x16x32_bf16(af[mf], bl, acc[mf][nf], 0, 0, 0);
      }
    }
  }
#pragma unroll
  for (int nf = 0; nf < 2; ++nf) {
    int col = (w * 2 + nf) * 16 + lo16;
#pragma unroll
    for (int mf = 0; mf < 4; ++mf) {
#pragma unroll
      for (int rr = 0; rr < 4; ++rr) {
        int row = m0 + mf * 16 + hi4 * 4 + rr;
        if (row < M) p.Y[(size_t)row * 128 + col] = f2bf(acc[mf][nf][rr]);
      }
    }
  }
}

__global__ __launch_bounds__(256) void k_histA(AArgs a) {
  __shared__ unsigned hbin[8192];  // 16384 packed u16 bins
  int bx = blockIdx.x;
  int t = threadIdx.x;
  if (bx < 208) {
    // din rank-histogram: block = (rel r, 16384-dst-range g, edge-chunk c)
    constexpr int DSTART[6] = {0, 64, 96, 160, 192, 208};
    constexpr int NDT[5] = {50000, 20000, 50000, 20000, 2000};
    constexpr int CS[5]  = {31250, 18750, 18750, 9375, 9375};
    constexpr int EE[5]  = {500000, 300000, 300000, 150000, 150000};
    constexpr int PB[5]  = {0, 800000, 1120000, 1920000, 2240000};
    constexpr int COFF[5] = {0, 500000, 800000, 1100000, 1250000};
    int r = 0;
    while (bx >= DSTART[r + 1]) ++r;
    int local = bx - DSTART[r];
    int g = local >> 4, c = local & 15;
    int nd = NDT[r];
    int gbase = g * 16384;
    int gend = gbase + 16384 < nd ? gbase + 16384 : nd;
    const int* dst = a.edst[r];
    int* pos = a.pos + COFF[r];
    int elo = c * CS[r];
    int ehi = elo + CS[r] < EE[r] ? elo + CS[r] : EE[r];
    for (int j = t; j < 8192; j += 256) hbin[j] = 0;
    __syncthreads();
    for (int e = elo + t; e < ehi; e += 256) {
      int d = dst[e];
      if (d >= gbase && d < gend) {
        int bin = d - gbase;
        int sh = (bin & 1) * 16;
        unsigned old = atomicAdd(&hbin[bin >> 1], 1u << sh);
        pos[e] = (int)((old >> sh) & 0xffffu);
      }
    }
    __syncthreads();
    int* out = a.partial + PB[r] + (size_t)c * nd + gbase;
    int nn = gend - gbase;
    for (int j = t; j < nn; j += 256)
      out[j] = (int)((hbin[j >> 1] >> ((j & 1) * 16)) & 0xffffu);
  } else if (bx < 416) {
    // dout histogram (counts only), same packing
    constexpr int OSTART[6] = {0, 64, 128, 160, 176, 208};
    constexpr int NST[5] = {50000, 50000, 20000, 2000, 20000};
    constexpr int CS[5]  = {31250, 18750, 18750, 9375, 9375};
    constexpr int EE[5]  = {500000, 300000, 300000, 150000, 150000};
    constexpr int PB[5]  = {2272000, 3072000, 3872000, 4192000, 4224000};
    int idx = bx - 208;
    int r = 0;
    while (idx >= OSTART[r + 1]) ++r;
    int local = idx - OSTART[r];
    int g = local >> 4, c = local & 15;
    int ns = NST[r];
    int gbase = g * 16384;
    int gend = gbase + 16384 < ns ? gbase + 16384 : ns;
    const int* src = a.esrc[r];
    int elo = c * CS[r];
    int ehi = elo + CS[r] < EE[r] ? elo + CS[r] : EE[r];
    for (int j = t; j < 8192; j += 256) hbin[j] = 0;
    __syncthreads();
    for (int e = elo + t; e < ehi; e += 256) {
      int s = src[e];
      if (s >= gbase && s < gend)
        atomicAdd(&hbin[(s - gbase) >> 1], 1u << (((s - gbase) & 1) * 16));
    }
    __syncthreads();
    int* out = a.partial + PB[r] + (size_t)c * ns + gbase;
    int nn = gend - gbase;
    for (int j = t; j < nn; j += 256)
      out[j] = (int)((hbin[j >> 1] >> ((j & 1) * 16)) & 0xffffu);
  } else if (bx < 2638) {
    constexpr int TSTART[6] = {0, 782, 1564, 1877, 1909, 2222};
    int ti = bx - 416, r = 0;
    while (ti >= TSTART[r + 1]) ++r;
    transform_body(a.tj[r], ti - TSTART[r], t);
  } else {
    int b = bx - 2638, ji = 0;
    while (ji < 7 && b >= a.pj[ji + 1].bstart) ++ji;
    PrepJob p = a.pj[ji];
    int eidx = (b - p.bstart) * 256 + t;
    int n = eidx >> 7, k = eidx & 127;
    if (n >= p.NOUT) return;
    float w = p.W0[k * p.NOUT + n];
    unsigned short h = f2bf(w);
    float res = w - bf2f(h);
    p.hi[n * 128 + k] = h;
    p.lo[n * 128 + k] = f2bf(res);
  }
}

// ---------------- phase B: chunk-prefix (din, in-place) + rs + cnt ----------------

struct BArgs { int* partial; int* cnt; float* rs; };

__global__ __launch_bounds__(256) void k_scanB(BArgs a) {
  int bx = blockIdx.x;
  int t = threadIdx.x;
  if (bx < 555) {
    int i = bx * 256 + t;
    if (i >= 142000) return;
    constexpr int NDT[5] = {50000, 20000, 50000, 20000, 2000};
    constexpr int PB[5]  = {0, 800000, 1120000, 1920000, 2240000};
    constexpr int DOFF[5] = {50000, 150000, 190000, 242000, 282000};
    int r, d;
    if      (i < 50000)  { r = 0; d = i; }
    else if (i < 70000)  { r = 1; d = i - 50000; }
    else if (i < 120000) { r = 2; d = i - 70000; }
    else if (i < 140000) { r = 3; d = i - 120000; }
    else                 { r = 4; d = i - 140000; }
    int nd = NDT[r];
    int* p = a.partial + PB[r] + d;
    int run = 0;
#pragma unroll
    for (int c = 0; c < 16; ++c) {
      int v = p[(size_t)c * nd];
      p[(size_t)c * nd] = run;
      run += v;
    }
    a.cnt[DOFF[r] + d] = run;
    a.rs[DOFF[r] + d] = rsqrtf((float)(run > 1 ? run : 1));
  } else {
    int i = (bx - 555) * 256 + t;
    if (i >= 142000) return;
    constexpr int NST[5] = {50000, 50000, 20000, 2000, 20000};
    constexpr int PB[5]  = {2272000, 3072000, 3872000, 4192000, 4224000};
    constexpr int OOFF[5] = {0, 100000, 170000, 240000, 262000};
    int r, s;
    if      (i < 50000)  { r = 0; s = i; }
    else if (i < 100000) { r = 1; s = i - 50000; }
    else if (i < 120000) { r = 2; s = i - 100000; }
    else if (i < 122000) { r = 3; s = i - 120000; }
    else                 { r = 4; s = i - 122000; }
    int ns = NST[r];
    const int* p = a.partial + PB[r] + s;
    int sum = 0;
#pragma unroll
    for (int c = 0; c < 16; ++c) sum += p[(size_t)c * ns];
    a.rs[OOFF[r] + s] = rsqrtf((float)(sum > 1 ? sum : 1));
  }
}

// ---------------- scan3: rp from cnt ----------------

struct S3Args { const int* cnt; int* rp; };

__global__ __launch_bounds__(256) void k_scan3(S3Args a) {
  constexpr int CSTART[6] = {0, 49, 69, 118, 138, 140};
  constexpr int NDT[5] = {50000, 20000, 50000, 20000, 2000};
  constexpr int DOFF[5] = {50000, 150000, 190000, 242000, 282000};
  constexpr int RPOFF[5] = {0, 50001, 70002, 120003, 140004};
  int bx = blockIdx.x, r = 0;
  while (bx >= CSTART[r + 1]) ++r;
  int chunk = bx - CSTART[r];
  int nch = CSTART[r + 1] - CSTART[r];
  int n = NDT[r];
  const int* cnt = a.cnt + DOFF[r];
  int* rp = a.rp + RPOFF[r];
  int t = threadIdx.x;
  __shared__ int sd[256];
  __shared__ int choff_sh;
  int lim = chunk * 1024;
  int pre = 0;
  for (int j = t; j < lim; j += 256) pre += cnt[j];
  sd[t] = pre;
  __syncthreads();
  for (int off = 128; off > 0; off >>= 1) {
    if (t < off) sd[t] += sd[t + off];
    __syncthreads();
  }
  if (t == 0) choff_sh = sd[0];
  __syncthreads();
  int idx0 = lim + t * 4;
  int v[4];
#pragma unroll
  for (int j = 0; j < 4; ++j) v[j] = (idx0 + j < n) ? cnt[idx0 + j] : 0;
  int tsum = v[0] + v[1] + v[2] + v[3];
  sd[t] = tsum;
  __syncthreads();
  for (int s = 1; s < 256; s <<= 1) {
    int add = (t >= s) ? sd[t - s] : 0;
    __syncthreads();
    sd[t] += add;
    __syncthreads();
  }
  int off = choff_sh + sd[t] - tsum;
#pragma unroll
  for (int j = 0; j < 4; ++j) {
    if (idx0 + j < n) rp[idx0 + j] = off;
    off += v[j];
  }
  if (chunk == nch - 1 && t == 255) rp[n] = choff_sh + sd[255];
}

// ---------------- phase C: atomic-free CSR scatter ----------------

struct CArgs { const int* esrc[5]; const int* edst[5]; const int* pos;
               const int* rp; const int* partial; int* csr; };

__global__ __launch_bounds__(256) void k_buildC(CArgs a) {
  constexpr int ESTART[6] = {0, 1954, 3126, 4298, 4884, 5470};
  constexpr int NDT[5] = {50000, 20000, 50000, 20000, 2000};
  constexpr int CS[5]  = {31250, 18750, 18750, 9375, 9375};
  constexpr int EE[5]  = {500000, 300000, 300000, 150000, 150000};
  constexpr int PB[5]  = {0, 800000, 1120000, 1920000, 2240000};
  constexpr int RPOFF[5] = {0, 50001, 70002, 120003, 140004};
  constexpr int COFF[5] = {0, 500000, 800000, 1100000, 1250000};
  int bx = blockIdx.x, r = 0;
  while (bx >= ESTART[r + 1]) ++r;
  int i = (bx - ESTART[r]) * 256 + threadIdx.x;
  if (i < EE[r]) {
    int d = a.edst[r][i];
    int c = i / CS[r];
    int slot = a.rp[RPOFF[r] + d] + a.partial[PB[r] + (size_t)c * NDT[r] + d]
             + a.pos[COFF[r] + i];
    a.csr[COFF[r] + slot] = a.esrc[r][i];
  }
}

// ---------------- shared gather inner loop ----------------

#define GROW(vv, cc)                                                              \
  _Pragma("unroll") for (int q = 0; q < 8; ++q)                                   \
      acc[q] = fmaf(__uint_as_float(((unsigned)(unsigned short)vv[q]) << 16), cc, acc[q]);

__device__ __forceinline__ void gat_accum(const int* __restrict__ rp,
    const int* __restrict__ csr, const unsigned short* __restrict__ Y,
    const float* __restrict__ rso, int wid, int sub, float* acc) {
  int e0 = rp[wid], e1 = rp[wid + 1];
  for (int base = e0; base < e1; base += 16) {
    int m = e1 - base;
    if (m > 16) m = 16;
    int ei = base + (sub < m ? sub : 0);
    int se = csr[ei];
    float sc = rso[se];
    if (m == 16) {
      bf16x8 v[16];
#pragma unroll
      for (int j = 0; j < 16; ++j) {
        int sj = __shfl(se, j, 16);
        v[j] = *(const bf16x8*)&Y[(size_t)sj * 128 + sub * 8];
      }
#pragma unroll
      for (int j = 0; j < 16; ++j) {
        float cj = __shfl(sc, j, 16);
        GROW(v[j], cj)
      }
    } else {
      int j = 0;
      for (; j + 8 <= m; j += 8) {
        int s0 = __shfl(se, j, 16), s1 = __shfl(se, j + 1, 16);
        int s2 = __shfl(se, j + 2, 16), s3 = __shfl(se, j + 3, 16);
        int s4 = __shfl(se, j + 4, 16), s5 = __shfl(se, j + 5, 16);
        int s6 = __shfl(se, j + 6, 16), s7 = __shfl(se, j + 7, 16);
        float c0 = __shfl(sc, j, 16), c1 = __shfl(sc, j + 1, 16);
        float c2 = __shfl(sc, j + 2, 16), c3 = __shfl(sc, j + 3, 16);
        float c4 = __shfl(sc, j + 4, 16), c5 = __shfl(sc, j + 5, 16);
        float c6 = __shfl(sc, j + 6, 16), c7 = __shfl(sc, j + 7, 16);
        bf16x8 v0 = *(const bf16x8*)&Y[(size_t)s0 * 128 + sub * 8];
        bf16x8 v1 = *(const bf16x8*)&Y[(size_t)s1 * 128 + sub * 8];
        bf16x8 v2 = *(const bf16x8*)&Y[(size_t)s2 * 128 + sub * 8];
        bf16x8 v3 = *(const bf16x8*)&Y[(size_t)s3 * 128 + sub * 8];
        bf16x8 v4 = *(const bf16x8*)&Y[(size_t)s4 * 128 + sub * 8];
        bf16x8 v5 = *(const bf16x8*)&Y[(size_t)s5 * 128 + sub * 8];
        bf16x8 v6 = *(const bf16x8*)&Y[(size_t)s6 * 128 + sub * 8];
        bf16x8 v7 = *(const bf16x8*)&Y[(size_t)s7 * 128 + sub * 8];
        GROW(v0, c0) GROW(v1, c1) GROW(v2, c2) GROW(v3, c3)
        GROW(v4, c4) GROW(v5, c5) GROW(v6, c6) GROW(v7, c7)
      }
      for (; j < m; ++j) {
        int s0 = __shfl(se, j, 16);
        float c0 = __shfl(sc, j, 16);
        bf16x8 v0 = *(const bf16x8*)&Y[(size_t)s0 * 128 + sub * 8];
        GROW(v0, c0)
      }
    }
  }
}

// ---------------- layer-1 gather: Y -> h1 bf16 (bias + mean + lrelu fused) ----------------

struct G1Rel { const int* rp; const int* csr; const unsigned short* Y;
               const float* rso; const float* rsi; };
struct G1Args { G1Rel rel[5]; const float* b;
                unsigned short* hU; unsigned short* hN; unsigned short* hS; };

__global__ __launch_bounds__(256) void k_gather1(G1Args a) {
  int bx = blockIdx.x;
  int t = threadIdx.x;
  int sub = t & 15;
  float acc[8], tot[8];
#pragma unroll
  for (int q = 0; q < 8; ++q) acc[q] = 0.f;
  if (bx < 3125) {  // users: rel 0 + rel 2
    int wid = bx * 16 + (t >> 4);
    gat_accum(a.rel[0].rp, a.rel[0].csr, a.rel[0].Y, a.rel[0].rso, wid, sub, acc);
    float s0 = a.rel[0].rsi[wid];
#pragma unroll
    for (int q = 0; q < 8; ++q) { tot[q] = s0 * acc[q]; acc[q] = 0.f; }
    gat_accum(a.rel[2].rp, a.rel[2].csr, a.rel[2].Y, a.rel[2].rso, wid, sub, acc);
    float s2 = a.rel[2].rsi[wid];
    const float* b0 = a.b;
    const float* b2 = a.b + 2 * 128;
    u16x8 o;
#pragma unroll
    for (int q = 0; q < 8; ++q) {
      float v = 0.5f * (tot[q] + s2 * acc[q] + b0[sub * 8 + q] + b2[sub * 8 + q]);
      v = v >= 0.f ? v : LRELU * v;
      o[q] = f2bf(v);
    }
    *(u16x8*)&a.hU[(size_t)wid * 128 + sub * 8] = o;
  } else if (bx < 4375) {  // news: rel 1 + rel 3
    int wid = (bx - 3125) * 16 + (t >> 4);
    gat_accum(a.rel[1].rp, a.rel[1].csr, a.rel[1].Y, a.rel[1].rso, wid, sub, acc);
    float s1 = a.rel[1].rsi[wid];
#pragma unroll
    for (int q = 0; q < 8; ++q) { tot[q] = s1 * acc[q]; acc[q] = 0.f; }
    gat_accum(a.rel[3].rp, a.rel[3].csr, a.rel[3].Y, a.rel[3].rso, wid, sub, acc);
    float s3 = a.rel[3].rsi[wid];
    const float* b1v = a.b + 128;
    const float* b3 = a.b + 3 * 128;
    u16x8 o;
#pragma unroll
    for (int q = 0; q < 8; ++q) {
      float v = 0.5f * (tot[q] + s3 * acc[q] + b1v[sub * 8 + q] + b3[sub * 8 + q]);
      v = v >= 0.f ? v : LRELU * v;
      o[q] = f2bf(v);
    }
    *(u16x8*)&a.hN[(size_t)wid * 128 + sub * 8] = o;
  } else {  // sources: rel 4
    int wid = (bx - 4375) * 16 + (t >> 4);
    gat_accum(a.rel[4].rp, a.rel[4].csr, a.rel[4].Y, a.rel[4].rso, wid, sub, acc);
    float s4 = a.rel[4].rsi[wid];
    const float* b4 = a.b + 4 * 128;
    u16x8 o;
#pragma unroll
    for (int q = 0; q < 8; ++q) {
      float v = s4 * acc[q] + b4[sub * 8 + q];
      v = v >= 0.f ? v : LRELU * v;
      o[q] = f2bf(v);
    }
    *(u16x8*)&a.hS[(size_t)wid * 128 + sub * 8] = o;
  }
}

// ---------------- MFMA GEMM body (prepped hi/lo W) ----------------

struct MJob { const unsigned short* A; const unsigned short* Wh; const unsigned short* Wl;
              const float* b0; const float* b1; float scale; int lrelu;
              float* H; int ldh; unsigned short* Hb; int M; int bstart; };

template <int KCH, int NW>
__device__ __forceinline__ void mgemm_body(const MJob& p, int bxl) {
  constexpr int KP = KCH * 128;
  int t = threadIdx.x;
  int w = t >> 6, l = t & 63;
  int lo16 = l & 15, hi4 = l >> 4;
  int m0 = bxl * 64;
  int M = p.M;
  const unsigned short* A = p.A;
  f32x4 acc[4][NW] = {};
  for (int s = 0; s < KP / 32; ++s) {
    int kbase = s * 32 + hi4 * 8;
    bf16x8 af[4];
#pragma unroll
    for (int mf = 0; mf < 4; ++mf) {
      int row = m0 + mf * 16 + lo16;
      row = row < M ? row : M - 1;  // clamp; OOB rows never stored
      af[mf] = *(const bf16x8*)&A[(size_t)row * KP + kbase];
    }
#pragma unroll
    for (int nf = 0; nf < NW; ++nf) {
      int n = (w * NW + nf) * 16 + lo16;
      bf16x8 bh = *(const bf16x8*)&p.Wh[(size_t)n * KP + kbase];
      bf16x8 bl = *(const bf16x8*)&p.Wl[(size_t)n * KP + kbase];
#pragma unroll
      for (int mf = 0; mf < 4; ++mf) {
        acc[mf][nf] = __builtin_amdgcn_mfma_f32_16x16x32_bf16(af[mf], bh, acc[mf][nf], 0, 0, 0);
        acc[mf][nf] = __builtin_amdgcn_mfma_f32_16x16x32_bf16(af[mf], bl, acc[mf][nf], 0, 0, 0);
      }
    }
  }
#pragma unroll
  for (int nf = 0; nf < NW; ++nf) {
    int col = (w * NW + nf) * 16 + lo16;
    float bs = p.b0 ? p.b0[col] : 0.f;
    if (p.b1) bs += p.b1[col];
#pragma unroll
    for (int mf = 0; mf < 4; ++mf) {
#pragma unroll
      for (int rr = 0; rr < 4; ++rr) {
        int row = m0 + mf * 16 + hi4 * 4 + rr;
        if (row < M) {
          float o = p.scale * (acc[mf][nf][rr] + bs);
          if (p.lrelu) o = o >= 0.f ? o : LRELU * o;
          if (p.H) p.H[(size_t)row * p.ldh + col] = o;
          if (p.Hb) p.Hb[(size_t)row * p.ldh + col] = f2bf(o);
        }
      }
    }
  }
}

// layer-2 transform: Y2_r = h1_src @ W2_r (5 jobs, one launch)
struct M5Args { MJob j[5]; };
__global__ __launch_bounds__(256) void k_trans5(M5Args a) {
  int bx = blockIdx.x;
  int ji = 0;
  while (ji < 4 && bx >= a.j[ji + 1].bstart) ++ji;
  mgemm_body<1, 2>(a.j[ji], bx - a.j[ji].bstart);
}

// output projections (3 jobs, one launch)
struct MArgs { MJob j[3]; };
__global__ __launch_bounds__(256) void k_proj3(MArgs a) {
  int bx = blockIdx.x;
  if (bx < a.j[1].bstart)      mgemm_body<1, 1>(a.j[0], bx);
  else if (bx < a.j[2].bstart) mgemm_body<1, 1>(a.j[1], bx - a.j[1].bstart);
  else                         mgemm_body<1, 1>(a.j[2], bx - a.j[2].bstart);
}

// ---------------- layer-2 gather: Y2 -> h2 (f32 + bf16, fused epilogue) ----------------

struct G2Args { G1Rel rel[5]; const float* b;
                float* HU; float* HN; float* HS;
                unsigned short* hU; unsigned short* hN; unsigned short* hS; };

__device__ __forceinline__ void g2_store(float* H, unsigned short* Hb,
                                         int wid, int sub, const float* v) {
  float4 f0 = {v[0], v[1], v[2], v[3]};
  float4 f1 = {v[4], v[5], v[6], v[7]};
  *(float4*)&H[(size_t)wid * 128 + sub * 8] = f0;
  *(float4*)&H[(size_t)wid * 128 + sub * 8 + 4] = f1;
  u16x8 o;
#pragma unroll
  for (int q = 0; q < 8; ++q) o[q] = f2bf(v[q]);
  *(u16x8*)&Hb[(size_t)wid * 128 + sub * 8] = o;
}

__global__ __launch_bounds__(256) void k_gather2(G2Args a) {
  int bx = blockIdx.x;
  int t = threadIdx.x;
  int sub = t & 15;
  float acc[8], tot[8], v[8];
#pragma unroll
  for (int q = 0; q < 8; ++q) acc[q] = 0.f;
  if (bx < 3125) {  // users: rel 0 + rel 2
    int wid = bx * 16 + (t >> 4);
    gat_accum(a.rel[0].rp, a.rel[0].csr, a.rel[0].Y, a.rel[0].rso, wid, sub, acc);
    float s0 = a.rel[0].rsi[wid];
#pragma unroll
    for (int q = 0; q < 8; ++q) { tot[q] = s0 * acc[q]; acc[q] = 0.f; }
    gat_accum(a.rel[2].rp, a.rel[2].csr, a.rel[2].Y, a.rel[2].rso, wid, sub, acc);
    float s2 = a.rel[2].rsi[wid];
    const float* b0 = a.b;
    const float* b2 = a.b + 2 * 128;
#pragma unroll
    for (int q = 0; q < 8; ++q) {
      float x = 0.5f * (tot[q] + s2 * acc[q] + b0[sub * 8 + q] + b2[sub * 8 + q]);
      v[q] = x >= 0.f ? x : LRELU * x;
    }
    g2_store(a.HU, a.hU, wid, sub, v);
  } else if (bx < 4375) {  // news: rel 1 + rel 3
    int wid = (bx - 3125) * 16 + (t >> 4);
    gat_accum(a.rel[1].rp, a.rel[1].csr, a.rel[1].Y, a.rel[1].rso, wid, sub, acc);
    float s1 = a.rel[1].rsi[wid];
#pragma unroll
    for (int q = 0; q < 8; ++q) { tot[q] = s1 * acc[q]; acc[q] = 0.f; }
    gat_accum(a.rel[3].rp, a.rel[3].csr, a.rel[3].Y, a.rel[3].rso, wid, sub, acc);
    float s3 = a.rel[3].rsi[wid];
    const float* b1v = a.b + 128;
    const float* b3 = a.b + 3 * 128;
#pragma unroll
    for (int q = 0; q < 8; ++q) {
      float x = 0.5f * (tot[q] + s3 * acc[q] + b1v[sub * 8 + q] + b3[sub * 8 + q]);
      v[q] = x >= 0.f ? x : LRELU * x;
    }
    g2_store(a.HN, a.hN, wid, sub, v);
  } else {  // sources: rel 4
    int wid = (bx - 4375) * 16 + (t >> 4);
    gat_accum(a.rel[4].rp, a.rel[4].csr, a.rel[4].Y, a.rel[4].rso, wid, sub, acc);
    float s4 = a.rel[4].rsi[wid];
    const float* b4 = a.b + 4 * 128;
#pragma unroll
    for (int q = 0; q < 8; ++q) {
      float x = s4 * acc[q] + b4[sub * 8 + q];
      v[q] = x >= 0.f ? x : LRELU * x;
    }
    g2_store(a.HS, a.hS, wid, sub, v);
  }
}

// ---------------- host ----------------

extern "C" void kernel_launch(void* const* d_in, const int* in_sizes, int n_in,
                              void* d_out, int out_size, void* d_ws, size_t ws_size,
                              hipStream_t stream) {
  const float* xu = (const float*)d_in[0];
  const float* xn = (const float*)d_in[1];
  const float* xs = (const float*)d_in[2];
  const float* W1 = (const float*)d_in[3];
  const float* b1 = (const float*)d_in[4];
  const float* W2 = (const float*)d_in[5];
  const float* b2 = (const float*)d_in[6];
  const float* Wu = (const float*)d_in[7];
  const float* bu = (const float*)d_in[8];
  const float* Wn = (const float*)d_in[9];
  const float* bn = (const float*)d_in[10];
  const float* Wsrc = (const float*)d_in[11];
  const float* bsrc = (const float*)d_in[12];
  const int* SRC[5] = {(const int*)d_in[13], (const int*)d_in[15], (const int*)d_in[17],
                       (const int*)d_in[19], (const int*)d_in[21]};
  const int* DST[5] = {(const int*)d_in[14], (const int*)d_in[16], (const int*)d_in[18],
                       (const int*)d_in[20], (const int*)d_in[22]};

  // ---- workspace layout ----
  int* ws_i = (int*)d_ws;
  int* rp = ws_i;                           // 142008
  int* csr = ws_i + 142008;                 // 1400000
  int* pos = ws_i + 1542008;                // 1400000
  int* cnt = ws_i + 2942328;                // 284000 (din slots used)
  float* rs = (float*)(ws_i + 3226328);     // 284000
  unsigned short* wt = (unsigned short*)(rs + 284000);    // 376832
  unsigned short* Y2region = wt + 376832;   // 18.176M ushorts (old agg region)
  unsigned short* xbU = Y2region + 18176000; // 50000*128 (h1 then h2, bf16)
  unsigned short* xbN = xbU + 6400000;      // 20000*128
  unsigned short* xbS = xbN + 2560000;      // 2000*128

  // Y2 sub-layout (layer-2 transform outputs, bf16)
  unsigned short* Y2_0 = Y2region;            // 50000*128 (xbU @ W2_0)
  unsigned short* Y2_1 = Y2_0 + 6400000;      // 50000*128 (xbU @ W2_1)
  unsigned short* Y2_2 = Y2_1 + 6400000;      // 20000*128 (xbN @ W2_2)
  unsigned short* Y2_4 = Y2_2 + 2560000;      // 20000*128 (xbN @ W2_4)
  unsigned short* Y2_3 = Y2_4 + 2560000;      // 2000*128  (xbS @ W2_3)

  // wt sub-offsets: 5x W2_r (hi,lo 16384 each) + 3 proj (hi,lo 8192 each)
  unsigned short* W2h[5], * W2l[5];
  for (int r = 0; r < 5; ++r) { W2h[r] = wt + r * 32768; W2l[r] = wt + r * 32768 + 16384; }
  unsigned short* PU_h = wt + 163840, * PU_l = wt + 172032;
  unsigned short* PN_h = wt + 180224, * PN_l = wt + 188416;
  unsigned short* PS_h = wt + 196608, * PS_l = wt + 204800;

  // ---- d_out layout ----
  float* outf = (float*)d_out;
  float* ou = outf;                 // 50000*64
  float* on = outf + 3200000;       // 20000*64
  float* osrc = outf + 4480000;     // 2000*64
  float* hu = outf + 4608000;       // 50000*128
  float* hn = outf + 11008000;      // 20000*128
  float* hs = outf + 13568000;      // 2000*128

  // histogram partials / chunk-bases: 4.544M ints in ou+on+osrc (4.608M f32),
  // dead until k_proj3; consumed by scanB/buildC.
  int* partial = (int*)outf;

  // layer-1 transform outputs Y_r (bf16) in hu/hn/hs region; consumed by
  // k_gather1, dead before k_gather2 writes hu/hn/hs.
  unsigned short* Yb = (unsigned short*)(outf + 4608000);
  unsigned short* Y0 = Yb;              // 50000*128 (follows, src U)
  unsigned short* Y1 = Y0 + 6400000;    // 50000*128 (posts, src U)
  unsigned short* Y2a = Y1 + 6400000;   // 20000*128 (posted_by, src N)
  unsigned short* Y3 = Y2a + 2560000;   // 2000*128  (publishes, src S)
  unsigned short* Y4 = Y3 + 256000;     // 20000*128 (published_by, src N)

  // ---- phase A: packed hists + transform(L1) + wprep ----
  AArgs aa;
  for (int r = 0; r < 5; ++r) { aa.esrc[r] = SRC[r]; aa.edst[r] = DST[r]; }
  aa.pos = pos;
  aa.partial = partial;
  aa.tj[0] = {xu, W1 + 0 * 16384, Y0, kNU};
  aa.tj[1] = {xu, W1 + 1 * 16384, Y1, kNU};
  aa.tj[2] = {xn, W1 + 2 * 16384, Y2a, kNN};
  aa.tj[3] = {xs, W1 + 3 * 16384, Y3, kNS};
  aa.tj[4] = {xn, W1 + 4 * 16384, Y4, kNN};
  for (int r = 0; r < 5; ++r)
    aa.pj[r] = {W2 + r * 16384, W2h[r], W2l[r], 128, r * 64};
  aa.pj[5] = {Wu, PU_h, PU_l, 64, 320};
  aa.pj[6] = {Wn, PN_h, PN_l, 64, 352};
  aa.pj[7] = {Wsrc, PS_h, PS_l, 64, 384};
  k_histA<<<3054, 256, 0, stream>>>(aa);

  // ---- phase B: chunk prefixes + rs + cnt ----
  BArgs ba = {partial, cnt, rs};
  k_scanB<<<1110, 256, 0, stream>>>(ba);

  // ---- rp scan ----
  S3Args s3 = {cnt, rp};
  k_scan3<<<140, 256, 0, stream>>>(s3);

  // ---- phase C: CSR scatter ----
  CArgs ca;
  for (int r = 0; r < 5; ++r) { ca.esrc[r] = SRC[r]; ca.edst[r] = DST[r]; }
  ca.pos = pos;
  ca.rp = rp;
  ca.partial = partial;
  ca.csr = csr;
  k_buildC<<<5470, 256, 0, stream>>>(ca);

  // ---- layer 1: gather Y -> h1 (bf16 into xb*) ----
  G1Args g1;
  const unsigned short* YT[5] = {Y0, Y1, Y2a, Y3, Y4};
  for (int r = 0; r < 5; ++r)
    g1.rel[r] = {rp + RP_OFF[r], csr + CSR_OFF[r], YT[r],
                 rs + DOUT_OFF[r], rs + DIN_OFF[r]};
  g1.b = b1;
  g1.hU = xbU; g1.hN = xbN; g1.hS = xbS;
  k_gather1<<<4500, 256, 0, stream>>>(g1);

  // ---- layer 2 transform: Y2_r = h1_src @ W2_r ----
  M5Args t5;
  t5.j[0] = {xbU, W2h[0], W2l[0], nullptr, nullptr, 1.0f, 0, nullptr, 128, Y2_0, kNU, 0};
  t5.j[1] = {xbU, W2h[1], W2l[1], nullptr, nullptr, 1.0f, 0, nullptr, 128, Y2_1, kNU, 782};
  t5.j[2] = {xbN, W2h[2], W2l[2], nullptr, nullptr, 1.0f, 0, nullptr, 128, Y2_2, kNN, 1564};
  t5.j[3] = {xbS, W2h[3], W2l[3], nullptr, nullptr, 1.0f, 0, nullptr, 128, Y2_3, kNS, 1877};
  t5.j[4] = {xbN, W2h[4], W2l[4], nullptr, nullptr, 1.0f, 0, nullptr, 128, Y2_4, kNN, 1909};
  k_trans5<<<2222, 256, 0, stream>>>(t5);

  // ---- layer 2 gather: Y2 -> h2 (f32 into d_out, bf16 into xb*) ----
  G2Args g2;
  const unsigned short* Y2T[5] = {Y2_0, Y2_1, Y2_2, Y2_3, Y2_4};
  for (int r = 0; r < 5; ++r)
    g2.rel[r] = {rp + RP_OFF[r], csr + CSR_OFF[r], Y2T[r],
                 rs + DOUT_OFF[r], rs + DIN_OFF[r]};
  g2.b = b2;
  g2.HU = hu; g2.HN = hn; g2.HS = hs;
  g2.hU = xbU; g2.hN = xbN; g2.hS = xbS;
  k_gather2<<<4500, 256, 0, stream>>>(g2);

  // ---- output projections (read bf16 h2 from xb*) ----
  MArgs pm;
  pm.j[0] = {xbU, PU_h, PU_l, bu, nullptr, 1.0f, 0, ou, 64, nullptr, kNU, 0};
  pm.j[1] = {xbN, PN_h, PN_l, bn, nullptr, 1.0f, 0, on, 64, nullptr, kNN, 782};
  pm.j[2] = {xbS, PS_h, PS_l, bsrc, nullptr, 1.0f, 0, osrc, 64, nullptr, kNS, 1095};
  k_proj3<<<1127, 256, 0, stream>>>(pm);
}